// Round 11
// baseline (318.374 us; speedup 1.0000x reference)
//
#include <hip/hip_runtime.h>
#include <hip/hip_fp16.h>

// GCN 2-layer. count (+rank) -> multi-block scan (fused rsqrt + degree
// histogram) -> atomic-free CSR fill -> degree-bucket node permutation ->
// [MFMA fp16 GEMM (scaled fp16 out) -> aggregate via perm] x2.
// out[i] = dis[i]*(scaled[i] + sum_j scaled[j]) + b, scaled[j]=dis[j]*(x@W)[j].
// Aggs pack 4/8 nodes per wave and loop to the max degree in the group;
// the degree-bucket permutation makes grouped degrees equal -> inflation ~1.0
// (was ~1.5x with random grouping). Per-node CSR sum order unchanged ->
// bit-identical output vs r10.

typedef _Float16 half8 __attribute__((ext_vector_type(8)));
typedef float floatx4 __attribute__((ext_vector_type(4)));

__global__ void k_count(const int* __restrict__ col, int* __restrict__ deg,
                        int* __restrict__ rank, int E) {
    int e = blockIdx.x * blockDim.x + threadIdx.x;
    if (e < E) rank[e] = atomicAdd(&deg[col[e]], 1);
}

// Per-chunk inclusive scan + dis = rsqrt(deg+1) + clamped-degree histogram.
__global__ __launch_bounds__(1024) void k_scan_local(const int* __restrict__ deg,
                                                     int* __restrict__ rowptr,
                                                     int* __restrict__ bsum,
                                                     float* __restrict__ dis,
                                                     int* __restrict__ hist, int n) {
    __shared__ int s[1024];
    __shared__ int lh[64];
    int b = blockIdx.x, tid = threadIdx.x;
    if (tid < 64) lh[tid] = 0;
    int i = b * 1024 + tid;
    int v = (i < n) ? deg[i] : 0;
    if (i < n) dis[i] = rsqrtf((float)v + 1.0f);  // +1 = self-loop
    s[tid] = v;
    __syncthreads();
    if (i < n) atomicAdd(&lh[min(v, 63)], 1);
    for (int off = 1; off < 1024; off <<= 1) {
        int t = (tid >= off) ? s[tid - off] : 0;
        __syncthreads();
        s[tid] += t;
        __syncthreads();
    }
    if (i < n) rowptr[i + 1] = s[tid];
    if (tid == 1023) bsum[b] = s[1023];
    if (b == 0 && tid == 0) rowptr[0] = 0;
    __syncthreads();
    if (tid < 64) atomicAdd(&hist[tid], lh[tid]);
}

__global__ __launch_bounds__(256) void k_scan_fix(int* __restrict__ rowptr,
                                                  const int* __restrict__ bsum, int n) {
    __shared__ int red[256];
    int b = blockIdx.x, tid = threadIdx.x;
    int partial = 0;
    for (int j = tid; j < b; j += 256) partial += bsum[j];
    red[tid] = partial;
    __syncthreads();
    for (int off = 128; off > 0; off >>= 1) {
        if (tid < off) red[tid] += red[tid + off];
        __syncthreads();
    }
    int offv = red[0];
    if (offv == 0) return;
#pragma unroll
    for (int r = 0; r < 4; ++r) {
        int i = b * 1024 + r * 256 + tid;
        if (i < n) rowptr[i + 1] += offv;
    }
}

// Atomic-free: position = rowptr[target] + precomputed rank.
__global__ void k_fill(const int* __restrict__ row, const int* __restrict__ col,
                       const int* __restrict__ rowptr, const int* __restrict__ rank,
                       int* __restrict__ csr, int E) {
    int e = blockIdx.x * blockDim.x + threadIdx.x;
    if (e < E) csr[rowptr[col[e]] + rank[e]] = row[e];
}

// Degree-bucket permutation: perm groups nodes of equal clamped degree.
// Each block re-derives bucket offsets from hist (wave-0 shfl scan, cheap).
__global__ __launch_bounds__(256) void k_perm(const int* __restrict__ deg,
                                              const int* __restrict__ hist,
                                              int* __restrict__ cursor,
                                              int* __restrict__ perm, int n) {
    __shared__ int boff[64];
    int tid = threadIdx.x;
    if (tid < 64) {
        int h = hist[tid];
        int v = h;
        for (int off = 1; off < 64; off <<= 1) {
            int t = __shfl_up(v, off);
            if (tid >= off) v += t;
        }
        boff[tid] = v - h;  // exclusive prefix
    }
    __syncthreads();
    int i = blockIdx.x * 256 + tid;
    if (i < n) {
        int b = min(deg[i], 63);
        int pos = boff[b] + atomicAdd(&cursor[b], 1);
        perm[pos] = i;
    }
}

// Y[M,N](fp16) = (X[M,128] @ W[128,N]) * scale[m].
// Block: 64 rows (4 waves x 16), all N cols. K=128 in 4 MFMA steps of 32.
// LDS Wt[n][k] fp16 as half2 dwords; 16B block (n,kblk) at dword
// n*64 + (kblk ^ (n&15))*4 (XOR swizzle -> <=2-way banks on b128 reads).
// Frags (m89/m118/m120): A[m=lane&15][k=quad*8+j], B[k=quad*8+j][n=lane&15],
// D row=quad*4+reg, col=lane&15.
template <int N, typename AT>
__global__ __launch_bounds__(256) void k_gemm_mfma(const AT* __restrict__ X,
                                                   const float* __restrict__ W,
                                                   const float* __restrict__ scale,
                                                   __half* __restrict__ Y, int M) {
    __shared__ __align__(16) __half2 wt[N * 64];
    int tid = threadIdx.x;
    for (int i = tid; i < N * 64; i += 256) {
        int nn = i & (N - 1);
        int k2 = i / N;  // k = 2*k2
        float w0 = W[(size_t)(2 * k2) * N + nn];
        float w1 = W[(size_t)(2 * k2 + 1) * N + nn];
        wt[nn * 64 + ((k2 >> 2) ^ (nn & 15)) * 4 + (k2 & 3)] = __floats2half2_rn(w0, w1);
    }
    __syncthreads();
    int wid = tid >> 6, lane = tid & 63;
    int col = lane & 15, quad = lane >> 4;
    int m_a = blockIdx.x * 64 + wid * 16 + col;
    bool a_ok = m_a < M;
    constexpr int NT = N / 16;
    floatx4 acc[NT] = {};
#pragma unroll
    for (int ks = 0; ks < 4; ++ks) {
        int k = ks * 32 + quad * 8;
        half8 af;
        if constexpr (sizeof(AT) == 4) {
            floatx4 a0 = {0.f, 0.f, 0.f, 0.f}, a1 = {0.f, 0.f, 0.f, 0.f};
            if (a_ok) {
                a0 = *(const floatx4*)&X[(size_t)m_a * 128 + k];
                a1 = *(const floatx4*)&X[(size_t)m_a * 128 + k + 4];
            }
            af = half8{(_Float16)a0[0], (_Float16)a0[1], (_Float16)a0[2], (_Float16)a0[3],
                       (_Float16)a1[0], (_Float16)a1[1], (_Float16)a1[2], (_Float16)a1[3]};
        } else {
            half8 t = {};
            if (a_ok) t = *(const half8*)(const void*)&X[(size_t)m_a * 128 + k];
            af = t;
        }
        int kblk = ks * 4 + quad;
#pragma unroll
        for (int nt = 0; nt < NT; ++nt) {
            int nn = nt * 16 + col;
            half8 bf = *(const half8*)(const void*)&wt[nn * 64 + (kblk ^ (nn & 15)) * 4];
            acc[nt] = __builtin_amdgcn_mfma_f32_16x16x32_f16(af, bf, acc[nt], 0, 0, 0);
        }
    }
    int mbase = blockIdx.x * 64 + wid * 16 + quad * 4;
    float s[4];
#pragma unroll
    for (int r = 0; r < 4; ++r) s[r] = (mbase + r < M) ? scale[mbase + r] : 0.f;
#pragma unroll
    for (int nt = 0; nt < NT; ++nt) {
#pragma unroll
        for (int r = 0; r < 4; ++r) {
            if (mbase + r < M)
                Y[(size_t)(mbase + r) * N + nt * 16 + col] = __float2half(acc[nt][r] * s[r]);
        }
    }
}

// F=128: 4 nodes/wave via perm (equal-degree groups). 16 lanes x 16B = one
// 256B row per gather instr; coop index load (one VMEM instr per 8 edges).
__global__ __launch_bounds__(256) void k_agg128(const __half* __restrict__ xw,
                                                const float* __restrict__ dis,
                                                const int* __restrict__ rowptr,
                                                const int* __restrict__ csr,
                                                const int* __restrict__ perm,
                                                const float* __restrict__ bias,
                                                __half* __restrict__ out, int n) {
    int tid = threadIdx.x;
    int lane = tid & 63;
    int q = lane >> 4, li = lane & 15;
    int qbase = lane & 48;
    int gidx = blockIdx.x * 16 + ((tid >> 6) << 2) + q;
    bool ok = gidx < n;
    int node = ok ? perm[gidx] : 0;
    float di = 0.f;
    int beg = 0, end = 0;
    if (ok) {
        di = dis[node];
        beg = rowptr[node];
        end = rowptr[node + 1];
    }
    int dg = end - beg;
    int m1 = max(dg, __shfl(dg, lane ^ 16));
    int mx = max(m1, __shfl(m1, lane ^ 32));  // max over the wave's 4 nodes
    const half8* rows = (const half8*)xw;     // 16 half8 per row
    float acc[8] = {};
    if (ok) {
        half8 sf = rows[(size_t)node * 16 + li];
#pragma unroll
        for (int f = 0; f < 8; ++f) acc[f] = (float)sf[f];
    }
    for (int i = 0; i < mx; i += 8) {
        int e = beg + i + (li & 7);
        int myidx = (e < end) ? csr[e] : 0;  // one VMEM instr per 8 edges
        half8 v[8];
#pragma unroll
        for (int j = 0; j < 8; ++j) {
            int s = __shfl(myidx, qbase + j);
            v[j] = rows[(size_t)s * 16 + li];
        }
#pragma unroll
        for (int j = 0; j < 8; ++j) {
            if (beg + i + j < end) {
#pragma unroll
                for (int f = 0; f < 8; ++f) acc[f] += (float)v[j][f];
            }
        }
    }
    if (ok) {
        floatx4 b0 = *(const floatx4*)&bias[li * 8];
        floatx4 b1 = *(const floatx4*)&bias[li * 8 + 4];
        half8 o;
#pragma unroll
        for (int f = 0; f < 4; ++f) o[f] = (_Float16)fmaxf(acc[f] * di + b0[f], 0.f);
#pragma unroll
        for (int f = 0; f < 4; ++f) o[4 + f] = (_Float16)fmaxf(acc[4 + f] * di + b1[f], 0.f);
        ((half8*)out)[(size_t)node * 16 + li] = o;
    }
}

// F=64: 8 nodes/wave via perm. 8 lanes x 16B = one 128B row per gather instr.
__global__ __launch_bounds__(256) void k_agg64(const __half* __restrict__ xw,
                                               const float* __restrict__ dis,
                                               const int* __restrict__ rowptr,
                                               const int* __restrict__ csr,
                                               const int* __restrict__ perm,
                                               const float* __restrict__ bias,
                                               float* __restrict__ out, int n) {
    int tid = threadIdx.x;
    int lane = tid & 63;
    int o8 = lane >> 3, li = lane & 7;
    int obase = lane & 56;
    int gidx = blockIdx.x * 32 + ((tid >> 6) << 3) + o8;
    bool ok = gidx < n;
    int node = ok ? perm[gidx] : 0;
    float di = 0.f;
    int beg = 0, end = 0;
    if (ok) {
        di = dis[node];
        beg = rowptr[node];
        end = rowptr[node + 1];
    }
    int dg = end - beg;
    int m1 = max(dg, __shfl(dg, lane ^ 8));
    int m2 = max(m1, __shfl(m1, lane ^ 16));
    int mx = max(m2, __shfl(m2, lane ^ 32));  // max over the wave's 8 nodes
    const half8* rows = (const half8*)xw;     // 8 half8 per row
    float acc[8] = {};
    if (ok) {
        half8 sf = rows[(size_t)node * 8 + li];
#pragma unroll
        for (int f = 0; f < 8; ++f) acc[f] = (float)sf[f];
    }
    for (int i = 0; i < mx; i += 8) {
        int e = beg + i + li;
        int myidx = (e < end) ? csr[e] : 0;  // one VMEM instr per 8 edges
        half8 v[8];
#pragma unroll
        for (int j = 0; j < 8; ++j) {
            int s = __shfl(myidx, obase + j);
            v[j] = rows[(size_t)s * 8 + li];
        }
#pragma unroll
        for (int j = 0; j < 8; ++j) {
            if (beg + i + j < end) {
#pragma unroll
                for (int f = 0; f < 8; ++f) acc[f] += (float)v[j][f];
            }
        }
    }
    if (ok) {
        floatx4 b0 = *(const floatx4*)&bias[li * 8];
        floatx4 b1 = *(const floatx4*)&bias[li * 8 + 4];
        floatx4 o0, o1;
#pragma unroll
        for (int f = 0; f < 4; ++f) o0[f] = acc[f] * di + b0[f];
#pragma unroll
        for (int f = 0; f < 4; ++f) o1[f] = acc[4 + f] * di + b1[f];
        *(floatx4*)&out[(size_t)node * 64 + li * 8] = o0;
        *(floatx4*)&out[(size_t)node * 64 + li * 8 + 4] = o1;
    }
}

extern "C" void kernel_launch(void* const* d_in, const int* in_sizes, int n_in,
                              void* d_out, int out_size, void* d_ws, size_t ws_size,
                              hipStream_t stream) {
    const float* x  = (const float*)d_in[0];
    const int*   ei = (const int*)d_in[1];
    const float* W1 = (const float*)d_in[2];
    const float* b1 = (const float*)d_in[3];
    const float* W2 = (const float*)d_in[4];
    const float* b2 = (const float*)d_in[5];
    float* out = (float*)d_out;

    const int n = in_sizes[0] / 128;   // 50000
    const int E = in_sizes[1] / 2;     // 800000
    const int* row = ei;
    const int* col = ei + E;
    const int NB = (n + 1023) / 1024;
    const int CB = (E + 255) / 256;
    const int GB = (n + 63) / 64;

    char* ws = (char*)d_ws;
    size_t off = 0;
    auto alloc = [&](size_t bytes) -> void* {
        void* p = ws + off;
        off += (bytes + 255) & ~(size_t)255;
        return p;
    };
    // deg + hist(64) + cursor(64) zeroed in one memset
    int*    deg    = (int*)alloc((size_t)(n + 128) * 4);
    int*    hist   = deg + n;
    int*    cursor = deg + n + 64;
    int*    rowptr = (int*)alloc((size_t)(n + 1) * 4);
    int*    bsum   = (int*)alloc((size_t)NB * 4);
    int*    rank   = (int*)alloc((size_t)E * 4);
    int*    csr    = (int*)alloc((size_t)E * 4);
    int*    perm   = (int*)alloc((size_t)n * 4);
    float*  dis    = (float*)alloc((size_t)n * 4);
    __half* xw1    = (__half*)alloc((size_t)n * 128 * 2);
    __half* h      = (__half*)alloc((size_t)n * 128 * 2);
    __half* xw2    = (__half*)alloc((size_t)n * 64 * 2);
    (void)ws_size;

    hipMemsetAsync(deg, 0, (size_t)(n + 128) * 4, stream);
    k_count<<<CB, 256, 0, stream>>>(col, deg, rank, E);
    k_scan_local<<<NB, 1024, 0, stream>>>(deg, rowptr, bsum, dis, hist, n);
    k_scan_fix<<<NB, 256, 0, stream>>>(rowptr, bsum, n);
    k_fill<<<CB, 256, 0, stream>>>(row, col, rowptr, rank, csr, E);
    k_perm<<<(n + 255) / 256, 256, 0, stream>>>(deg, hist, cursor, perm, n);

    k_gemm_mfma<128, float><<<GB, 256, 0, stream>>>(x, W1, dis, xw1, n);
    k_agg128<<<(n + 15) / 16, 256, 0, stream>>>(xw1, dis, rowptr, csr, perm, b1, h, n);
    k_gemm_mfma<64, __half><<<GB, 256, 0, stream>>>(h, W2, dis, xw2, n);
    k_agg64<<<(n + 31) / 32, 256, 0, stream>>>(xw2, dis, rowptr, csr, perm, b2, out, n);
}

// Round 12
// 205.254 us; speedup vs baseline: 1.5511x; 1.5511x over previous
//
#include <hip/hip_runtime.h>
#include <hip/hip_fp16.h>

// GCN 2-layer. count (+rank) -> multi-block shfl-scan (fused rsqrt) ->
// [fused scan_fix || MFMA gemm1] -> atomic-free CSR fill -> agg128 ->
// gemm2 -> agg64.
// out[i] = dis[i]*(scaled[i] + sum_j scaled[j]) + b, scaled[j]=dis[j]*(x@W)[j]
// written fp16 by the GEMM epilogue.
// History: r7 weighted-CSR int2 -11us (reverted); r9 one-block scan 133us
// (reverted); r11 degree-bucket perm: 107us atomic-contention disaster AND
// falsified the batching-inflation theory (aggs unchanged) — aggs are at
// their gather sector-throughput floor. r12 = r10 + shfl scan + fix||gemm1
// fusion (scan_fix is 49 blocks, so gemm1's 32KB LDS can't starve it — the
// r7 failure mode needed thousands of co-scheduled latency-bound blocks).

typedef _Float16 half8 __attribute__((ext_vector_type(8)));
typedef float floatx4 __attribute__((ext_vector_type(4)));

__global__ void k_count(const int* __restrict__ col, int* __restrict__ deg,
                        int* __restrict__ rank, int E) {
    int e = blockIdx.x * blockDim.x + threadIdx.x;
    if (e < E) rank[e] = atomicAdd(&deg[col[e]], 1);
}

// Per-chunk inclusive scan via wave shfl (2 barriers) + dis = rsqrt(deg+1).
__global__ __launch_bounds__(1024) void k_scan_local(const int* __restrict__ deg,
                                                     int* __restrict__ rowptr,
                                                     int* __restrict__ bsum,
                                                     float* __restrict__ dis, int n) {
    __shared__ int wsum[16];
    int b = blockIdx.x, tid = threadIdx.x;
    int lane = tid & 63, w = tid >> 6;
    int i = b * 1024 + tid;
    int v = (i < n) ? deg[i] : 0;
    if (i < n) dis[i] = rsqrtf((float)v + 1.0f);  // +1 = self-loop
    int sc = v;
#pragma unroll
    for (int off = 1; off < 64; off <<= 1) {
        int t = __shfl_up(sc, off);
        if (lane >= off) sc += t;
    }
    if (lane == 63) wsum[w] = sc;
    __syncthreads();
    if (w == 0) {
        int s = (lane < 16) ? wsum[lane] : 0;
#pragma unroll
        for (int off = 1; off < 16; off <<= 1) {
            int t = __shfl_up(s, off);
            if (lane >= off) s += t;
        }
        if (lane < 16) wsum[lane] = s;
    }
    __syncthreads();
    int incl = sc + ((w > 0) ? wsum[w - 1] : 0);
    if (i < n) rowptr[i + 1] = incl;
    if (tid == 1023) bsum[b] = incl;
    if (b == 0 && tid == 0) rowptr[0] = 0;
}

// Y[M,N](fp16) = (X[M,128] @ W[128,N]) * scale[m].
// Block: 64 rows (4 waves x 16), all N cols. K=128 in 4 MFMA steps of 32.
// LDS Wt[n][k] fp16 as half2 dwords; 16B block (n,kblk) at dword
// n*64 + (kblk ^ (n&15))*4 (XOR swizzle -> <=2-way banks on b128 reads).
// Frags (m89/m118/m120): A[m=lane&15][k=quad*8+j], B[k=quad*8+j][n=lane&15],
// D row=quad*4+reg, col=lane&15.
template <int N, typename AT>
__device__ __forceinline__ void gemm_tile(const AT* __restrict__ X,
                                          const float* __restrict__ W,
                                          const float* __restrict__ scale,
                                          __half* __restrict__ Y, int M,
                                          int m0, __half2* wt, int tid) {
    for (int i = tid; i < N * 64; i += 256) {
        int nn = i & (N - 1);
        int k2 = i / N;  // k = 2*k2
        float w0 = W[(size_t)(2 * k2) * N + nn];
        float w1 = W[(size_t)(2 * k2 + 1) * N + nn];
        wt[nn * 64 + ((k2 >> 2) ^ (nn & 15)) * 4 + (k2 & 3)] = __floats2half2_rn(w0, w1);
    }
    __syncthreads();
    int wid = tid >> 6, lane = tid & 63;
    int col = lane & 15, quad = lane >> 4;
    int m_a = m0 + wid * 16 + col;
    bool a_ok = m_a < M;
    constexpr int NT = N / 16;
    floatx4 acc[NT] = {};
#pragma unroll
    for (int ks = 0; ks < 4; ++ks) {
        int k = ks * 32 + quad * 8;
        half8 af;
        if constexpr (sizeof(AT) == 4) {
            floatx4 a0 = {0.f, 0.f, 0.f, 0.f}, a1 = {0.f, 0.f, 0.f, 0.f};
            if (a_ok) {
                a0 = *(const floatx4*)&X[(size_t)m_a * 128 + k];
                a1 = *(const floatx4*)&X[(size_t)m_a * 128 + k + 4];
            }
            af = half8{(_Float16)a0[0], (_Float16)a0[1], (_Float16)a0[2], (_Float16)a0[3],
                       (_Float16)a1[0], (_Float16)a1[1], (_Float16)a1[2], (_Float16)a1[3]};
        } else {
            half8 t = {};
            if (a_ok) t = *(const half8*)(const void*)&X[(size_t)m_a * 128 + k];
            af = t;
        }
        int kblk = ks * 4 + quad;
#pragma unroll
        for (int nt = 0; nt < NT; ++nt) {
            int nn = nt * 16 + col;
            half8 bf = *(const half8*)(const void*)&wt[nn * 64 + (kblk ^ (nn & 15)) * 4];
            acc[nt] = __builtin_amdgcn_mfma_f32_16x16x32_f16(af, bf, acc[nt], 0, 0, 0);
        }
    }
    int mbase = m0 + wid * 16 + quad * 4;
    float s[4];
#pragma unroll
    for (int r = 0; r < 4; ++r) s[r] = (mbase + r < M) ? scale[mbase + r] : 0.f;
#pragma unroll
    for (int nt = 0; nt < NT; ++nt) {
#pragma unroll
        for (int r = 0; r < 4; ++r) {
            if (mbase + r < M)
                Y[(size_t)(mbase + r) * N + nt * 16 + col] = __float2half(acc[nt][r] * s[r]);
        }
    }
}

// Fused: blocks [0,FB) apply scan_fix (cross-chunk prefix); blocks [FB,...)
// run gemm1. Independent inputs; scan_fix is only ~49 blocks so the 32KB
// LDS can't occupancy-starve it.
__global__ __launch_bounds__(256) void k_fix_gemm1(int* __restrict__ rowptr,
                                                   const int* __restrict__ bsum, int n,
                                                   const float* __restrict__ X,
                                                   const float* __restrict__ W,
                                                   const float* __restrict__ scale,
                                                   __half* __restrict__ Y, int M, int FB) {
    __shared__ __align__(16) __half2 wt[128 * 64];  // 32 KB (gemm); reused by fix
    int b = blockIdx.x, tid = threadIdx.x;
    if (b < FB) {
        int* red = (int*)wt;
        int partial = 0;
        for (int j = tid; j < b; j += 256) partial += bsum[j];
        red[tid] = partial;
        __syncthreads();
        for (int off = 128; off > 0; off >>= 1) {
            if (tid < off) red[tid] += red[tid + off];
            __syncthreads();
        }
        int offv = red[0];
        if (offv == 0) return;
#pragma unroll
        for (int r = 0; r < 4; ++r) {
            int i = b * 1024 + r * 256 + tid;
            if (i < n) rowptr[i + 1] += offv;
        }
        return;
    }
    gemm_tile<128, float>(X, W, scale, Y, M, (b - FB) * 64, wt, tid);
}

__global__ __launch_bounds__(256) void k_gemm2(const __half* __restrict__ X,
                                               const float* __restrict__ W,
                                               const float* __restrict__ scale,
                                               __half* __restrict__ Y, int M) {
    __shared__ __align__(16) __half2 wt[64 * 64];  // 16 KB
    gemm_tile<64, __half>(X, W, scale, Y, M, blockIdx.x * 64, wt, threadIdx.x);
}

// Atomic-free: position = rowptr[target] + precomputed rank.
__global__ void k_fill(const int* __restrict__ row, const int* __restrict__ col,
                       const int* __restrict__ rowptr, const int* __restrict__ rank,
                       int* __restrict__ csr, int E) {
    int e = blockIdx.x * blockDim.x + threadIdx.x;
    if (e < E) csr[rowptr[col[e]] + rank[e]] = row[e];
}

// F=128: 4 nodes/wave (16 lanes x 16B = one 256B row per gather instr).
// Cooperative index load: one VMEM instr per 8 edges, __shfl redistribute.
__global__ __launch_bounds__(256) void k_agg128(const __half* __restrict__ xw,
                                                const float* __restrict__ dis,
                                                const int* __restrict__ rowptr,
                                                const int* __restrict__ csr,
                                                const float* __restrict__ bias,
                                                __half* __restrict__ out, int n) {
    int tid = threadIdx.x;
    int lane = tid & 63;
    int q = lane >> 4, li = lane & 15;
    int qbase = lane & 48;
    int node = blockIdx.x * 16 + ((tid >> 6) << 2) + q;
    bool ok = node < n;
    float di = 0.f;
    int beg = 0, end = 0;
    if (ok) {
        di = dis[node];
        beg = rowptr[node];
        end = rowptr[node + 1];
    }
    int dg = end - beg;
    int m1 = max(dg, __shfl(dg, lane ^ 16));
    int mx = max(m1, __shfl(m1, lane ^ 32));  // max over the wave's 4 nodes
    const half8* rows = (const half8*)xw;     // 16 half8 per row
    float acc[8] = {};
    if (ok) {
        half8 sf = rows[(size_t)node * 16 + li];
#pragma unroll
        for (int f = 0; f < 8; ++f) acc[f] = (float)sf[f];
    }
    for (int i = 0; i < mx; i += 8) {
        int e = beg + i + (li & 7);
        int myidx = (e < end) ? csr[e] : 0;  // one VMEM instr per 8 edges
        half8 v[8];
#pragma unroll
        for (int j = 0; j < 8; ++j) {
            int s = __shfl(myidx, qbase + j);
            v[j] = rows[(size_t)s * 16 + li];
        }
#pragma unroll
        for (int j = 0; j < 8; ++j) {
            if (beg + i + j < end) {
#pragma unroll
                for (int f = 0; f < 8; ++f) acc[f] += (float)v[j][f];
            }
        }
    }
    if (ok) {
        floatx4 b0 = *(const floatx4*)&bias[li * 8];
        floatx4 b1 = *(const floatx4*)&bias[li * 8 + 4];
        half8 o;
#pragma unroll
        for (int f = 0; f < 4; ++f) o[f] = (_Float16)fmaxf(acc[f] * di + b0[f], 0.f);
#pragma unroll
        for (int f = 0; f < 4; ++f) o[4 + f] = (_Float16)fmaxf(acc[4 + f] * di + b1[f], 0.f);
        ((half8*)out)[(size_t)node * 16 + li] = o;
    }
}

// F=64: 8 nodes/wave (8 lanes x 16B = one 128B row per gather instr).
__global__ __launch_bounds__(256) void k_agg64(const __half* __restrict__ xw,
                                               const float* __restrict__ dis,
                                               const int* __restrict__ rowptr,
                                               const int* __restrict__ csr,
                                               const float* __restrict__ bias,
                                               float* __restrict__ out, int n) {
    int tid = threadIdx.x;
    int lane = tid & 63;
    int o8 = lane >> 3, li = lane & 7;
    int obase = lane & 56;
    int node = blockIdx.x * 32 + ((tid >> 6) << 3) + o8;
    bool ok = node < n;
    float di = 0.f;
    int beg = 0, end = 0;
    if (ok) {
        di = dis[node];
        beg = rowptr[node];
        end = rowptr[node + 1];
    }
    int dg = end - beg;
    int m1 = max(dg, __shfl(dg, lane ^ 8));
    int m2 = max(m1, __shfl(m1, lane ^ 16));
    int mx = max(m2, __shfl(m2, lane ^ 32));  // max over the wave's 8 nodes
    const half8* rows = (const half8*)xw;     // 8 half8 per row
    float acc[8] = {};
    if (ok) {
        half8 sf = rows[(size_t)node * 8 + li];
#pragma unroll
        for (int f = 0; f < 8; ++f) acc[f] = (float)sf[f];
    }
    for (int i = 0; i < mx; i += 8) {
        int e = beg + i + li;
        int myidx = (e < end) ? csr[e] : 0;  // one VMEM instr per 8 edges
        half8 v[8];
#pragma unroll
        for (int j = 0; j < 8; ++j) {
            int s = __shfl(myidx, obase + j);
            v[j] = rows[(size_t)s * 8 + li];
        }
#pragma unroll
        for (int j = 0; j < 8; ++j) {
            if (beg + i + j < end) {
#pragma unroll
                for (int f = 0; f < 8; ++f) acc[f] += (float)v[j][f];
            }
        }
    }
    if (ok) {
        floatx4 b0 = *(const floatx4*)&bias[li * 8];
        floatx4 b1 = *(const floatx4*)&bias[li * 8 + 4];
        floatx4 o0, o1;
#pragma unroll
        for (int f = 0; f < 4; ++f) o0[f] = acc[f] * di + b0[f];
#pragma unroll
        for (int f = 0; f < 4; ++f) o1[f] = acc[4 + f] * di + b1[f];
        *(floatx4*)&out[(size_t)node * 64 + li * 8] = o0;
        *(floatx4*)&out[(size_t)node * 64 + li * 8 + 4] = o1;
    }
}

extern "C" void kernel_launch(void* const* d_in, const int* in_sizes, int n_in,
                              void* d_out, int out_size, void* d_ws, size_t ws_size,
                              hipStream_t stream) {
    const float* x  = (const float*)d_in[0];
    const int*   ei = (const int*)d_in[1];
    const float* W1 = (const float*)d_in[2];
    const float* b1 = (const float*)d_in[3];
    const float* W2 = (const float*)d_in[4];
    const float* b2 = (const float*)d_in[5];
    float* out = (float*)d_out;

    const int n = in_sizes[0] / 128;   // 50000
    const int E = in_sizes[1] / 2;     // 800000
    const int* row = ei;
    const int* col = ei + E;
    const int NB = (n + 1023) / 1024;
    const int CB = (E + 255) / 256;
    const int GB = (n + 63) / 64;

    char* ws = (char*)d_ws;
    size_t off = 0;
    auto alloc = [&](size_t bytes) -> void* {
        void* p = ws + off;
        off += (bytes + 255) & ~(size_t)255;
        return p;
    };
    int*    deg    = (int*)alloc((size_t)n * 4);
    int*    rowptr = (int*)alloc((size_t)(n + 1) * 4);
    int*    bsum   = (int*)alloc((size_t)NB * 4);
    int*    rank   = (int*)alloc((size_t)E * 4);
    int*    csr    = (int*)alloc((size_t)E * 4);
    float*  dis    = (float*)alloc((size_t)n * 4);
    __half* xw1    = (__half*)alloc((size_t)n * 128 * 2);
    __half* h      = (__half*)alloc((size_t)n * 128 * 2);
    __half* xw2    = (__half*)alloc((size_t)n * 64 * 2);
    (void)ws_size;

    hipMemsetAsync(deg, 0, (size_t)n * 4, stream);
    k_count<<<CB, 256, 0, stream>>>(col, deg, rank, E);
    k_scan_local<<<NB, 1024, 0, stream>>>(deg, rowptr, bsum, dis, n);
    k_fix_gemm1<<<NB + GB, 256, 0, stream>>>(rowptr, bsum, n, x, W1, dis, xw1, n, NB);
    k_fill<<<CB, 256, 0, stream>>>(row, col, rowptr, rank, csr, E);

    k_agg128<<<(n + 15) / 16, 256, 0, stream>>>(xw1, dis, rowptr, csr, b1, h, n);
    k_gemm2<<<GB, 256, 0, stream>>>(h, W2, dis, xw2, n);
    k_agg64<<<(n + 31) / 32, 256, 0, stream>>>(xw2, dis, rowptr, csr, b2, out, n);
}